// Round 2
// baseline (624.519 us; speedup 1.0000x reference)
//
#include <hip/hip_runtime.h>
#include <cstdint>
#include <cstddef>

// Problem constants
#define NB 8
#define TT 2048
#define DD 512
#define FF 2048
#define NE 16
#define NT (NB*TT)              // 16384 tokens
#define NPOS (NT*2)             // 32768 dispatch slots (K=2)
#define MT_MAX (NPOS/128 + NE)  // 272 max M-tiles (sum of per-expert ceil(c/128))
#define NPAL (MT_MAX*128)       // 34816 padded positions

typedef short v8s __attribute__((ext_vector_type(8)));   // 8 x bf16 bits (4 VGPRs)
typedef float v4f __attribute__((ext_vector_type(4)));

__device__ __forceinline__ uint16_t f2bf(float v) {
  union { float f; uint32_t u; } c; c.f = v;
  uint32_t r = (c.u + 0x7FFFu + ((c.u >> 16) & 1u)) >> 16;   // RNE
  return (uint16_t)r;
}
__device__ __forceinline__ float bf2f(uint16_t b) {
  union { uint32_t u; float f; } c; c.u = ((uint32_t)b) << 16;
  return c.f;
}
__device__ __forceinline__ float gelu_t(float x) {  // jax.nn.gelu approximate=True
  float u = 0.7978845608028654f * (x + 0.044715f * x * x * x);
  return 0.5f * x * (1.0f + tanhf(u));
}
__device__ __forceinline__ void gl_lds16(const void* g, void* l) {
  __builtin_amdgcn_global_load_lds(
      (const __attribute__((address_space(1))) uint32_t*)g,
      (__attribute__((address_space(3))) uint32_t*)l, 16, 0, 0);
}

// ---------------- zero small scratch ----------------
__global__ void k_zero(int* p, int n) {
  for (int i = threadIdx.x; i < n; i += 256) p[i] = 0;
}

// ---------------- x fp32 -> bf16 ----------------
__global__ __launch_bounds__(256) void k_cvt_x(const float* __restrict__ x,
                                               uint16_t* __restrict__ xb) {
  int i = (blockIdx.x * 256 + threadIdx.x) * 4;
  const float4 v = *(const float4*)(x + i);
  ushort4 o; o.x = f2bf(v.x); o.y = f2bf(v.y); o.z = f2bf(v.z); o.w = f2bf(v.w);
  *(ushort4*)(xb + i) = o;
}

// ---------------- transpose + convert weights: dst[e][c][r] = src[e][r][c] ----------------
__global__ __launch_bounds__(256) void k_trans(const float* __restrict__ src,
                                               uint16_t* __restrict__ dst,
                                               int rows, int cols) {
  __shared__ float t[32][33];
  const size_t eo = (size_t)blockIdx.z * rows * cols;
  const float* s = src + eo;
  uint16_t* d = dst + eo;
  int c0 = blockIdx.x * 32, r0 = blockIdx.y * 32;
  int tx = threadIdx.x, ty = threadIdx.y;
#pragma unroll
  for (int i = 0; i < 4; ++i)
    t[ty + i * 8][tx] = s[(size_t)(r0 + ty + i * 8) * cols + c0 + tx];
  __syncthreads();
#pragma unroll
  for (int i = 0; i < 4; ++i)
    d[(size_t)(c0 + ty + i * 8) * rows + r0 + tx] = f2bf(t[tx][ty + i * 8]);
}

// ---------------- router (fp64 logits for exact top-k agreement) ----------------
__global__ __launch_bounds__(256) void k_router(
    const float* __restrict__ x, const float* __restrict__ Wr,
    int* __restrict__ topi, float* __restrict__ gates,
    int* __restrict__ cnt_part, int* __restrict__ f_part, float* __restrict__ P_part) {
  __shared__ int s_cnt[NE]; __shared__ int s_f[NE]; __shared__ float s_P[NE];
  const int tid = threadIdx.x;
  if (tid < NE) { s_cnt[tid] = 0; s_f[tid] = 0; s_P[tid] = 0.f; }
  __syncthreads();
  const int wid = tid >> 6, lane = tid & 63;
  const int t = blockIdx.x * 4 + wid;
  const float* xr = x + (size_t)t * DD + lane * 8;
  double pe[NE];
#pragma unroll
  for (int e = 0; e < NE; ++e) pe[e] = 0.0;
#pragma unroll
  for (int j = 0; j < 8; ++j) {
    const double xv = (double)xr[j];
    const float* wr = Wr + (size_t)(lane * 8 + j) * NE;
#pragma unroll
    for (int e = 0; e < NE; ++e) pe[e] += xv * (double)wr[e];
  }
#pragma unroll
  for (int m = 1; m < 64; m <<= 1) {
#pragma unroll
    for (int e = 0; e < NE; ++e) pe[e] += __shfl_xor(pe[e], m, 64);
  }
  if (lane == 0) {
    double mx = pe[0];
#pragma unroll
    for (int e = 1; e < NE; ++e) mx = fmax(mx, pe[e]);
    double s = 0.0, pr[NE];
#pragma unroll
    for (int e = 0; e < NE; ++e) { pr[e] = exp(pe[e] - mx); s += pr[e]; }
    const double inv = 1.0 / s;
    int i0 = 0; double v0 = pe[0];
#pragma unroll
    for (int e = 1; e < NE; ++e) if (pe[e] > v0) { v0 = pe[e]; i0 = e; }
    int i1 = -1; double v1 = -1.0e300;
#pragma unroll
    for (int e = 0; e < NE; ++e) if (e != i0 && pe[e] > v1) { v1 = pe[e]; i1 = e; }
    const double g0 = 1.0 / (1.0 + exp(v1 - v0));
    topi[t * 2] = i0; topi[t * 2 + 1] = i1;
    gates[t * 2] = (float)g0; gates[t * 2 + 1] = (float)(1.0 - g0);
    atomicAdd(&s_cnt[i0], 1); atomicAdd(&s_cnt[i1], 1);
    atomicAdd(&s_f[i0], 1);
#pragma unroll
    for (int e = 0; e < NE; ++e) atomicAdd(&s_P[e], (float)(pr[e] * inv));
  }
  __syncthreads();
  if (tid < NE) {
    const int slot = (blockIdx.x & 63) * NE + tid;
    if (s_cnt[tid]) atomicAdd(&cnt_part[slot], s_cnt[tid]);
    if (s_f[tid]) atomicAdd(&f_part[slot], s_f[tid]);
    atomicAdd(&P_part[slot], s_P[tid]);
  }
}

// ---------------- reduce partials -> counts, aligned offsets, aux loss, pad fill ----------------
__global__ __launch_bounds__(256) void k_reduce(
    const int* __restrict__ cnt_part, const int* __restrict__ f_part,
    const float* __restrict__ P_part, int* __restrict__ counts,
    int* __restrict__ goff, int* __restrict__ cursor,
    int* __restrict__ tokofp, float* __restrict__ aux_out) {
  __shared__ int sc[NE]; __shared__ int sgo[NE + 1]; __shared__ double sterm[NE];
  const int tid = threadIdx.x;
  if (tid < NE) {
    int c = 0, f = 0; float P = 0.f;
    for (int s = 0; s < 64; ++s) {
      c += cnt_part[s * NE + tid]; f += f_part[s * NE + tid]; P += P_part[s * NE + tid];
    }
    counts[tid] = c; sc[tid] = c;
    sterm[tid] = ((double)f / NT) * ((double)P / NT);
  }
  __syncthreads();
  if (tid == 0) {
    double a = 0;
    for (int e = 0; e < NE; ++e) a += sterm[e];
    *aux_out = (float)(NE * a);
    int o = 0; sgo[0] = 0;
    for (int e = 0; e < NE; ++e) { o += ((sc[e] + 127) >> 7) << 7; sgo[e + 1] = o; }
    for (int e = 0; e <= NE; ++e) goff[e] = sgo[e];
    for (int e = 0; e < NE; ++e) cursor[e] = sgo[e];
  }
  __syncthreads();
  for (int e = 0; e < NE; ++e) {
    const int st = sgo[e] + sc[e], en = sgo[e + 1];
    for (int i = st + tid; i < en; i += 256) tokofp[i] = 0;  // padded rows gather token 0
  }
}

// ---------------- build per-expert token lists ----------------
__global__ __launch_bounds__(256) void k_build(const int* __restrict__ topi,
                                               int* __restrict__ cursor,
                                               int* __restrict__ tokofp,
                                               int* __restrict__ pos) {
  __shared__ int scnt[NE]; __shared__ int sbase[NE];
  const int tid = threadIdx.x;
  const int t = blockIdx.x * 256 + tid;
  if (tid < NE) scnt[tid] = 0;
  __syncthreads();
  const int e0 = topi[t * 2], e1 = topi[t * 2 + 1];
  const int r0 = atomicAdd(&scnt[e0], 1);
  const int r1 = atomicAdd(&scnt[e1], 1);
  __syncthreads();
  if (tid < NE) sbase[tid] = scnt[tid] ? atomicAdd(&cursor[tid], scnt[tid]) : 0;
  __syncthreads();
  const int p0 = sbase[e0] + r0, p1 = sbase[e1] + r1;
  tokofp[p0] = t; tokofp[p1] = t;
  pos[t * 2] = p0; pos[t * 2 + 1] = p1;
}

// ---------------- 128x128x64 bf16 MFMA GEMM over per-expert row lists ----------------
// GATHER_GELU=true : A = xb gathered via tokofp (K=512),  epilogue gelu -> h
// GATHER_GELU=false: A = h rows direct (K=2048),          epilogue bias -> ybuf
template <int KDIM, int NDIM, bool GATHER_GELU>
__global__ __launch_bounds__(256) void k_gemm(
    const uint16_t* __restrict__ Abase, const uint16_t* __restrict__ Bt,
    const float* __restrict__ bias, uint16_t* __restrict__ Cout,
    const int* __restrict__ goff, const int* __restrict__ tokofp) {
  __shared__ __align__(16) uint16_t As[128 * 64];
  __shared__ __align__(16) uint16_t Bs[128 * 64];
  const int gy = blockIdx.y;
  if (gy >= (goff[NE] >> 7)) return;
  int e = 0;
#pragma unroll
  for (int i = 1; i < NE; ++i) if (gy >= (goff[i] >> 7)) e = i;
  const int row0 = gy << 7;
  const int n0 = blockIdx.x << 7;
  const int tid = threadIdx.x, wid = tid >> 6, lane = tid & 63;

  // staging pointers: lane covers LDS bytes chunk*1024 + lane*16 (linear dest),
  // global source column pre-XOR-swizzled so swizzled ds_reads see logical data (T2)
  const uint16_t* aptr[4]; const uint16_t* bptr[4];
  uint16_t* asml[4]; uint16_t* bsml[4];
  const uint16_t* Be = Bt + (size_t)e * ((size_t)NDIM * KDIM);
#pragma unroll
  for (int i = 0; i < 4; ++i) {
    const int chunk = i * 4 + wid;
    const int row = chunk * 8 + (lane >> 3);
    const int kb = ((lane & 7) << 4) ^ ((row & 7) << 4);
    const int ks = kb >> 1;
    asml[i] = &As[chunk * 512];
    bsml[i] = &Bs[chunk * 512];
    size_t arow;
    if (GATHER_GELU) arow = (size_t)tokofp[row0 + row] * KDIM;
    else             arow = (size_t)(row0 + row) * KDIM;
    aptr[i] = Abase + arow + ks;
    bptr[i] = Be + (size_t)(n0 + row) * KDIM + ks;
  }

  // fragment read byte-offsets (XOR-swizzled)
  const int wm = wid >> 1, wn = wid & 1;
  int aoff[4][2], boff[4][2];
#pragma unroll
  for (int f = 0; f < 4; ++f) {
    const int ra = wm * 64 + f * 16 + (lane & 15);
    const int rb = wn * 64 + f * 16 + (lane & 15);
#pragma unroll
    for (int kk = 0; kk < 2; ++kk) {
      const int kb = kk * 64 + ((lane >> 4) << 4);
      aoff[f][kk] = ra * 128 + (kb ^ ((ra & 7) << 4));
      boff[f][kk] = rb * 128 + (kb ^ ((rb & 7) << 4));
    }
  }

  v4f acc[4][4];
#pragma unroll
  for (int i = 0; i < 4; ++i)
#pragma unroll
    for (int j = 0; j < 4; ++j) acc[i][j] = (v4f){0.f, 0.f, 0.f, 0.f};

  const int nkt = KDIM / 64;
  for (int kt = 0; kt < nkt; ++kt) {
#pragma unroll
    for (int i = 0; i < 4; ++i) gl_lds16(aptr[i] + kt * 64, asml[i]);
#pragma unroll
    for (int i = 0; i < 4; ++i) gl_lds16(bptr[i] + kt * 64, bsml[i]);
    __syncthreads();
#pragma unroll
    for (int kk = 0; kk < 2; ++kk) {
      v8s af[4], bfr[4];
#pragma unroll
      for (int f = 0; f < 4; ++f) af[f] = *(const v8s*)((const char*)As + aoff[f][kk]);
#pragma unroll
      for (int f = 0; f < 4; ++f) bfr[f] = *(const v8s*)((const char*)Bs + boff[f][kk]);
#pragma unroll
      for (int fm = 0; fm < 4; ++fm)
#pragma unroll
        for (int fn = 0; fn < 4; ++fn)
          acc[fm][fn] = __builtin_amdgcn_mfma_f32_16x16x32_bf16(af[fm], bfr[fn], acc[fm][fn], 0, 0, 0);
    }
    __syncthreads();
  }

  // epilogue: C layout col=lane&15, row=(lane>>4)*4+j
#pragma unroll
  for (int fn = 0; fn < 4; ++fn) {
    const int col = n0 + wn * 64 + fn * 16 + (lane & 15);
    const float bv = bias[e * NDIM + col];
#pragma unroll
    for (int fm = 0; fm < 4; ++fm) {
      const int rb = row0 + wm * 64 + fm * 16 + ((lane >> 4) << 2);
#pragma unroll
      for (int j = 0; j < 4; ++j) {
        float v = acc[fm][fn][j] + bv;
        if (GATHER_GELU) v = gelu_t(v);
        Cout[(size_t)(rb + j) * NDIM + col] = f2bf(v);
      }
    }
  }
}

// ---------------- combine: out[t] = g0*y[pos0] + g1*y[pos1] ----------------
__global__ __launch_bounds__(256) void k_comb(const uint16_t* __restrict__ ybuf,
                                              const int* __restrict__ pos,
                                              const float* __restrict__ gates,
                                              float* __restrict__ out) {
  const int t = blockIdx.x;
  const int d = threadIdx.x * 2;
  const float g0 = gates[t * 2], g1 = gates[t * 2 + 1];
  const uint32_t u0 = *(const uint32_t*)(ybuf + (size_t)pos[t * 2] * DD + d);
  const uint32_t u1 = *(const uint32_t*)(ybuf + (size_t)pos[t * 2 + 1] * DD + d);
  const float o0 = g0 * bf2f((uint16_t)u0) + g1 * bf2f((uint16_t)u1);
  const float o1 = g0 * bf2f((uint16_t)(u0 >> 16)) + g1 * bf2f((uint16_t)(u1 >> 16));
  *(float2*)(out + (size_t)t * DD + d) = make_float2(o0, o1);
}

extern "C" void kernel_launch(void* const* d_in, const int* in_sizes, int n_in,
                              void* d_out, int out_size, void* d_ws, size_t ws_size,
                              hipStream_t stream) {
  const float* x  = (const float*)d_in[0];
  const float* Wr = (const float*)d_in[1];
  const float* W1 = (const float*)d_in[2];
  const float* b1 = (const float*)d_in[3];
  const float* W2 = (const float*)d_in[4];
  const float* b2 = (const float*)d_in[5];
  float* out = (float*)d_out;

  char* ws = (char*)d_ws;
  size_t o = 0;
  auto alloc = [&](size_t bytes) { size_t r = o; o += (bytes + 255) & ~(size_t)255; return r; };
  uint16_t* xb    = (uint16_t*)(ws + alloc((size_t)NT * DD * 2));       // 16 MB
  uint16_t* W1T   = (uint16_t*)(ws + alloc((size_t)NE * FF * DD * 2));  // 32 MB  [E][F][D]
  uint16_t* W2T   = (uint16_t*)(ws + alloc((size_t)NE * DD * FF * 2));  // 32 MB  [E][D][F]
  uint16_t* h     = (uint16_t*)(ws + alloc((size_t)NPAL * FF * 2));     // 136 MB
  uint16_t* ybuf  = (uint16_t*)(ws + alloc((size_t)NPAL * DD * 2));     // 34 MB
  int*   cnt_part = (int*)(ws + alloc(64 * NE * 4));
  int*   f_part   = (int*)(ws + alloc(64 * NE * 4));
  float* P_part   = (float*)(ws + alloc(64 * NE * 4));
  int*   topi     = (int*)(ws + alloc((size_t)NT * 2 * 4));
  float* gatesb   = (float*)(ws + alloc((size_t)NT * 2 * 4));
  int*   pos      = (int*)(ws + alloc((size_t)NT * 2 * 4));
  int*   tokofp   = (int*)(ws + alloc((size_t)NPAL * 4));
  int*   counts   = (int*)(ws + alloc(NE * 4));
  int*   goff     = (int*)(ws + alloc((NE + 1) * 4));
  int*   cursor   = (int*)(ws + alloc(NE * 4));
  (void)ws_size; (void)in_sizes; (void)n_in; (void)out_size; (void)counts;

  k_zero<<<1, 256, 0, stream>>>(cnt_part, 3 * 64 * NE);  // cnt/f/P partials are contiguous
  k_cvt_x<<<NT * DD / 1024, 256, 0, stream>>>(x, xb);
  k_trans<<<dim3(FF / 32, DD / 32, NE), dim3(32, 8), 0, stream>>>(W1, W1T, DD, FF);
  k_trans<<<dim3(DD / 32, FF / 32, NE), dim3(32, 8), 0, stream>>>(W2, W2T, FF, DD);
  k_router<<<NT / 4, 256, 0, stream>>>(x, Wr, topi, gatesb, cnt_part, f_part, P_part);
  k_reduce<<<1, 256, 0, stream>>>(cnt_part, f_part, P_part, counts, goff, cursor,
                                  tokofp, out + (size_t)NT * DD);
  k_build<<<NT / 256, 256, 0, stream>>>(topi, cursor, tokofp, pos);
  k_gemm<DD, FF, true><<<dim3(FF / 128, MT_MAX), 256, 0, stream>>>(xb, W1T, b1, h, goff, tokofp);
  k_gemm<FF, DD, false><<<dim3(DD / 128, MT_MAX), 256, 0, stream>>>(h, W2T, b2, ybuf, goff, tokofp);
  k_comb<<<NT, 256, 0, stream>>>(ybuf, pos, gatesb, out);
}